// Round 7
// baseline (256.804 us; speedup 1.0000x reference)
//
#include <hip/hip_runtime.h>
#include <math.h>

#define TT   16
#define BB   64
#define DG   256
#define DH   512
#define DOUT 256

typedef unsigned long long u64t;

__device__ __forceinline__ float dot4(float4 a, float4 b) {
    return fmaf(a.x, b.x, fmaf(a.y, b.y, fmaf(a.z, b.z, a.w * b.w)));
}

__device__ __forceinline__ float blk_sum(float v, float* red, int tid) {
#pragma unroll
    for (int off = 32; off > 0; off >>= 1) v += __shfl_down(v, off, 64);
    if ((tid & 63) == 0) red[tid >> 6] = v;
    __syncthreads();
    float s = ((red[0] + red[1]) + (red[2] + red[3])) +
              ((red[4] + red[5]) + (red[6] + red[7]));
    __syncthreads();
    return s;
}

__device__ __forceinline__ float2 blk_sum2(float a, float b, float* red, int tid) {
#pragma unroll
    for (int off = 32; off > 0; off >>= 1) {
        a += __shfl_down(a, off, 64);
        b += __shfl_down(b, off, 64);
    }
    if ((tid & 63) == 0) { red[tid >> 6] = a; red[8 + (tid >> 6)] = b; }
    __syncthreads();
    float sa = ((red[0] + red[1]) + (red[2] + red[3])) +
               ((red[4] + red[5]) + (red[6] + red[7]));
    float sb = ((red[8] + red[9]) + (red[10] + red[11])) +
               ((red[12] + red[13]) + (red[14] + red[15]));
    __syncthreads();
    return make_float2(sa, sb);
}

// ---------- ONE kernel: 256 blocks = 64 batches x 4 output strips ----------
__global__ __launch_bounds__(512, 2) void rnn7(
    const float* __restrict__ z,      // [T][B][DG]
    const float* __restrict__ clean,  // [B][DOUT]
    const float* __restrict__ Wh,     // [DH][DH]
    const float* __restrict__ Wg,     // [DH][DG]
    const float* __restrict__ bh,
    const float* __restrict__ lng,
    const float* __restrict__ lnb,
    const float* __restrict__ alphap,
    const float* __restrict__ Whead,  // [DOUT][DH]
    const float* __restrict__ bhead,
    u64t* gpart,                      // [2][B][DH] tagged (tag<<32)|f32bits
    u64t* ssdp, u64t* cosp,           // [B] tagged loss partials
    float* __restrict__ out)
{
    __shared__ __align__(16) float u_lds[(TT - 1) * DH];  // 30 KB (prologue aliases first 16 KB as z staging)
    __shared__ __align__(16) float zp_lds[TT * 128];      // 8 KB zproj+bh for our strip
    __shared__ __align__(16) float h_lds[DH];
    __shared__ __align__(16) float hb_lds[DH];
    __shared__ __align__(16) float mpart[512];
    __shared__ __align__(16) float ppart[DH];
    __shared__ float G16[16][16];                         // Gram matrix u_i . u_j
    __shared__ float e_lds[16];                           // e_i = u_i.h  (slot nu = |h|^2)
    __shared__ float f_lds[16];                           // f_i = u_i.hb
    __shared__ float S_lds[16];                           // S_i = sum(u_i)
    __shared__ float red[16];

    const int tid  = threadIdx.x;
    const int b    = blockIdx.x & 63;
    const int q    = blockIdx.x >> 6;     // output strip [128q, 128q+128)
    const int lane = tid & 63;
    const int wid  = tid >> 6;

    // ---------------- prologue: zproj for our strip ----------------
    {
        float* z_s = u_lds;               // alias 16 KB
        for (int f = tid; f < TT * 64; f += 512)
            ((float4*)z_s)[f] = ((const float4*)z)[(size_t)(f >> 6) * (BB * 64) + b * 64 + (f & 63)];
        __syncthreads();
        const int r  = tid & 127;
        const int tq = tid >> 7;          // 4 t's per thread
        const float4* wrow = (const float4*)(Wg + (size_t)((q << 7) + r) * DG);
        float a0 = 0.f, a1 = 0.f, a2 = 0.f, a3 = 0.f;
        for (int j = 0; j < 64; ++j) {
            float4 w = wrow[j];
            a0 += dot4(w, ((const float4*)z_s)[(4 * tq + 0) * 64 + j]);
            a1 += dot4(w, ((const float4*)z_s)[(4 * tq + 1) * 64 + j]);
            a2 += dot4(w, ((const float4*)z_s)[(4 * tq + 2) * 64 + j]);
            a3 += dot4(w, ((const float4*)z_s)[(4 * tq + 3) * 64 + j]);
        }
        float bhr = bh[(q << 7) + r];
        zp_lds[(4 * tq + 0) * 128 + r] = a0 + bhr;
        zp_lds[(4 * tq + 1) * 128 + r] = a1 + bhr;
        zp_lds[(4 * tq + 2) * 128 + r] = a2 + bhr;
        zp_lds[(4 * tq + 3) * 128 + r] = a3 + bhr;
        __syncthreads();                  // z_s (u_lds) free after this
    }

    const float al   = alphap[0];
    const float kexp = (al >= 0.f) ? (1.f + log1pf(expf(al)))
                                   : (1.f / (1.f + log1pf(expf(-al))));
    const float gj = lng[tid];
    const float bj = lnb[tid];

    // ---- W_h strip: row (q<<7)+(tid&127), cols [(tid>>7)*128, +128) -> 128 AGPRs ----
    float wa[128];
    {
        const float* src = Wh + (size_t)((q << 7) + (tid & 127)) * DH + ((tid >> 7) << 7);
#pragma unroll
        for (int k = 0; k < 128; k += 4) {
            float4 v = *(const float4*)(src + k);
            asm volatile("v_accvgpr_write_b32 %0, %1" : "=a"(wa[k + 0]) : "v"(v.x));
            asm volatile("v_accvgpr_write_b32 %0, %1" : "=a"(wa[k + 1]) : "v"(v.y));
            asm volatile("v_accvgpr_write_b32 %0, %1" : "=a"(wa[k + 2]) : "v"(v.z));
            asm volatile("v_accvgpr_write_b32 %0, %1" : "=a"(wa[k + 3]) : "v"(v.w));
        }
    }

    float cv[TT - 1];                     // per-thread decay coefficients (redundant, registers)
#pragma unroll
    for (int i = 0; i < TT - 1; ++i) cv[i] = 0.f;

    float h = 0.f, hb = 0.f;

#pragma unroll 1
    for (int t = 0; t < TT; ++t) {
        // ---------------- matvec partials (t>0): kq uniform per wave -> broadcast ----------------
        if (t > 0) {
            const int kq = tid >> 7;
            float acc = 0.f;
#pragma unroll
            for (int k4 = 0; k4 < 32; ++k4) {
                float4 h4 = ((const float4*)h_lds)[(kq << 5) + k4];
                float w0, w1, w2, w3;
                asm("v_accvgpr_read_b32 %0, %1" : "=v"(w0) : "a"(wa[4 * k4 + 0]));
                asm("v_accvgpr_read_b32 %0, %1" : "=v"(w1) : "a"(wa[4 * k4 + 1]));
                asm("v_accvgpr_read_b32 %0, %1" : "=v"(w2) : "a"(wa[4 * k4 + 2]));
                asm("v_accvgpr_read_b32 %0, %1" : "=v"(w3) : "a"(wa[4 * k4 + 3]));
                acc = fmaf(w0, h4.x, fmaf(w1, h4.y, fmaf(w2, h4.z, fmaf(w3, h4.w, acc))));
            }
            mpart[tid] = acc;
        }
        __syncthreads();                  // B1: mpart ready

        // ---------------- tagged exchange ----------------
        const unsigned tag = (unsigned)(t + 1);
        u64t* gb = gpart + ((size_t)(t & 1) * BB + b) * DH;
        if (tid < 128) {
            float m = zp_lds[t * 128 + tid];
            if (t > 0)
                m += (mpart[tid] + mpart[tid + 128]) + (mpart[tid + 256] + mpart[tid + 384]);
            u64t pk = ((u64t)tag << 32) | (u64t)__float_as_uint(m);
            __hip_atomic_store(gb + (q << 7) + tid, pk, __ATOMIC_RELAXED, __HIP_MEMORY_SCOPE_AGENT);
        }
        if (t == TT - 1 && q != 0) return;    // non-head strips done

        // prefetch own-dim poll load; Gram work overlaps its latency
        u64t v = __hip_atomic_load(gb + tid, __ATOMIC_RELAXED, __HIP_MEMORY_SCOPE_AGENT);

        // ---------------- Gram row for u_{t-1} (overlapped with exchange) ----------------
        if (t >= 1) {
            const float* un = u_lds + (size_t)(t - 1) * DH;
#pragma unroll
            for (int rep = 0; rep < 2; ++rep) {
                int i = wid + (rep << 3);
                if (i <= t) {             // i<t: G[t-1][i]; i==t: S[t-1]
                    float a = 0.f;
                    if (i < t) {
#pragma unroll
                        for (int k = 0; k < 8; ++k)
                            a = fmaf(un[k * 64 + lane], u_lds[(size_t)i * DH + k * 64 + lane], a);
                    } else {
#pragma unroll
                        for (int k = 0; k < 8; ++k) a += un[k * 64 + lane];
                    }
#pragma unroll
                    for (int m = 32; m > 0; m >>= 1) a += __shfl_xor(a, m, 64);
                    if (lane == 0) {
                        if (i < t) { G16[t - 1][i] = a; G16[i][t - 1] = a; }
                        else       S_lds[t - 1] = a;
                    }
                }
            }
        }

        // ---------------- finish poll ----------------
        while ((unsigned)(v >> 32) != tag) {
            __builtin_amdgcn_s_sleep(1);
            v = __hip_atomic_load(gb + tid, __ATOMIC_RELAXED, __HIP_MEMORY_SCOPE_AGENT);
        }
        hb = __uint_as_float((unsigned)v);
        hb_lds[tid] = hb;
        __syncthreads();                  // B2: hb_lds + Gram visible

        const bool fin = (t == TT - 1);
        const int  nu  = fin ? (TT - 1) : t;

        // ---------------- LN stats + f_i = u_i.hb (one round) ----------------
        {
            float s1 = hb, s2 = hb * hb;
#pragma unroll
            for (int m = 32; m > 0; m >>= 1) {
                s1 += __shfl_xor(s1, m, 64);
                s2 += __shfl_xor(s2, m, 64);
            }
            if (lane == 0) { red[wid * 2] = s1; red[wid * 2 + 1] = s2; }
#pragma unroll
            for (int rep = 0; rep < 2; ++rep) {
                int i = wid + (rep << 3);
                if (i < nu) {
                    float a = 0.f;
#pragma unroll
                    for (int k = 0; k < 8; ++k)
                        a = fmaf(u_lds[(size_t)i * DH + k * 64 + lane], hb_lds[k * 64 + lane], a);
#pragma unroll
                    for (int m = 32; m > 0; m >>= 1) a += __shfl_xor(a, m, 64);
                    if (lane == 0) f_lds[i] = a;
                }
            }
        }
        __syncthreads();                  // B3: LN partials + f ready

        float S_hb = 0.f, S_hb2 = 0.f;
#pragma unroll
        for (int w = 0; w < 8; ++w) { S_hb += red[w * 2]; S_hb2 += red[w * 2 + 1]; }
        {
            float mu  = S_hb * (1.f / DH);
            float var = S_hb2 * (1.f / DH) - mu * mu;
            h = fmaxf((hb - mu) * rsqrtf(var + 1e-5f) * gj + bj, 0.f);
        }
        h_lds[tid] = h;
        if (t == 0) u_lds[tid] = h;       // u_0
        __syncthreads();                  // B4: h (and u_0) visible

        // ---------------- settle: 3 iters, ONE reduction round each ----------------
        if (t > 0) {
#pragma unroll 1
            for (int s = 0; s < 3; ++s) {
                // e_i = u_i.h (i<nu); task nu: |h|^2
#pragma unroll
                for (int rep = 0; rep < 2; ++rep) {
                    int i = wid + (rep << 3);
                    if (i <= nu) {
                        const float* uv = (i < nu) ? (u_lds + (size_t)i * DH) : h_lds;
                        float a = 0.f;
#pragma unroll
                        for (int k = 0; k < 8; ++k)
                            a = fmaf(uv[k * 64 + lane], h_lds[k * 64 + lane], a);
#pragma unroll
                        for (int m = 32; m > 0; m >>= 1) a += __shfl_xor(a, m, 64);
                        if (lane == 0) e_lds[i] = a;
                    }
                }
                __syncthreads();          // B5: e ready

                // scalar phase (redundant per thread; LDS broadcasts)
                float d[TT - 1];
#pragma unroll
                for (int i = 0; i < TT - 1; ++i) d[i] = (i < nu) ? cv[i] * e_lds[i] : 0.f;

                float hAh = 0.f, SAh = 0.f, hbAh = 0.f, AhAh = 0.f;
#pragma unroll
                for (int i = 0; i < TT - 1; ++i) {
                    if (i < nu) {
                        hAh  = fmaf(d[i], e_lds[i], hAh);
                        SAh  = fmaf(d[i], S_lds[i], SAh);
                        hbAh = fmaf(d[i], f_lds[i], hbAh);
                        float m = d[i] * G16[i][i];
#pragma unroll
                        for (int j = 0; j < i; ++j)
                            m = fmaf(2.f * d[j], G16[i][j], m);
                        AhAh = fmaf(d[i], m, AhAh);
                    }
                }

                float aa, c1;
                if (!fin) {
                    float hh = e_lds[nu];
                    float n1 = fmaxf(sqrtf(hh),   1e-6f);
                    float n2 = fmaxf(sqrtf(AhAh), 1e-6f);
                    float R  = fminf(fmaxf(hAh / (n1 * n2), 0.f), 1.f);
                    aa = 1.f - __builtin_amdgcn_exp2f(kexp * __builtin_amdgcn_logf(1.f - R));
                    c1 = 1.f - aa * aa;
                } else { aa = 1.f; c1 = 1.f; }

                float Sx   = c1 * S_hb + aa * SAh;
                float Sx2  = c1 * c1 * S_hb2 + 2.f * c1 * aa * hbAh + aa * aa * AhAh;
                float mu2  = Sx * (1.f / DH);
                float var2 = Sx2 * (1.f / DH) - mu2 * mu2;
                float rs2  = rsqrtf(var2 + 1e-5f);

                float Ah = 0.f;
#pragma unroll
                for (int i = 0; i < TT - 1; ++i)
                    if (i < nu) Ah = fmaf(d[i], u_lds[(size_t)i * DH + tid], Ah);

                float x = c1 * hb + aa * Ah;
                h = fmaxf((x - mu2) * rs2 * gj + bj, 0.f);
                h_lds[tid] = h;
                if (s == 2 && !fin) u_lds[(size_t)t * DH + tid] = h;
                __syncthreads();          // B6: h updated (u_t appended on last iter)
            }
        }

        // decay coefficients (per-thread registers, static unroll)
        if (t < TT - 1) {
#pragma unroll
            for (int i = 0; i < TT - 1; ++i) {
                if (i < t)       cv[i] *= 0.95f;
                else if (i == t) cv[i] = 0.5f;
            }
        }
    }

    // ---------------- head + per-batch loss (q==0 only reaches here) ----------------
    {
        const int oj   = tid & 255;
        const int half = tid >> 8;
        const float4* wr = (const float4*)(Whead + (size_t)oj * DH + half * 256);
        const float4* hv = ((const float4*)h_lds) + half * 64;
        float acc = 0.f;
#pragma unroll 4
        for (int i4 = 0; i4 < 64; ++i4) {
            float4 w  = wr[i4];
            float4 h4 = hv[i4];
            acc += w.x * h4.x + w.y * h4.y + w.z * h4.z + w.w * h4.w;
        }
        ppart[tid] = acc;
        __syncthreads();

        float pred = 0.f, tg = 0.f;
        if (tid < DOUT) {
            pred = ppart[tid] + ppart[tid + 256] + bhead[tid];
            tg   = clean[(size_t)b * DOUT + tid];
        }
        float pss = blk_sum(pred * pred, red, tid);
        float tss = blk_sum(tg * tg, red, tid);
        float pn = pred / (sqrtf(pss) + 1e-6f);
        float tn = tg   / (sqrtf(tss) + 1e-6f);
        float dd = pn - tn;
        float2 lc = blk_sum2(dd * dd, pn * tn, red, tid);
        if (tid == 0) {
            u64t pk = ((u64t)81u << 32) | (u64t)__float_as_uint(lc.x);
            __hip_atomic_store(ssdp + b, pk, __ATOMIC_RELAXED, __HIP_MEMORY_SCOPE_AGENT);
            pk = ((u64t)81u << 32) | (u64t)__float_as_uint(lc.y);
            __hip_atomic_store(cosp + b, pk, __ATOMIC_RELAXED, __HIP_MEMORY_SCOPE_AGENT);
        }
    }

    // ---------------- finisher: block 0, wave 0 ----------------
    if (blockIdx.x == 0 && wid == 0) {
        u64t va = __hip_atomic_load(ssdp + lane, __ATOMIC_RELAXED, __HIP_MEMORY_SCOPE_AGENT);
        while ((unsigned)(va >> 32) != 81u) {
            __builtin_amdgcn_s_sleep(1);
            va = __hip_atomic_load(ssdp + lane, __ATOMIC_RELAXED, __HIP_MEMORY_SCOPE_AGENT);
        }
        u64t vc = __hip_atomic_load(cosp + lane, __ATOMIC_RELAXED, __HIP_MEMORY_SCOPE_AGENT);
        while ((unsigned)(vc >> 32) != 81u) {
            __builtin_amdgcn_s_sleep(1);
            vc = __hip_atomic_load(cosp + lane, __ATOMIC_RELAXED, __HIP_MEMORY_SCOPE_AGENT);
        }
        float a = __uint_as_float((unsigned)va);
        float c = __uint_as_float((unsigned)vc);
#pragma unroll
        for (int m = 32; m > 0; m >>= 1) {
            a += __shfl_xor(a, m, 64);
            c += __shfl_xor(c, m, 64);
        }
        if (lane == 0) {
            out[0] = a * (1.f / (BB * DOUT));
            out[1] = c * (1.f / BB);
        }
    }
}

extern "C" void kernel_launch(void* const* d_in, const int* in_sizes, int n_in,
                              void* d_out, int out_size, void* d_ws, size_t ws_size,
                              hipStream_t stream) {
    const float* z     = (const float*)d_in[0];
    const float* clean = (const float*)d_in[1];
    const float* Wh    = (const float*)d_in[2];
    const float* Wg    = (const float*)d_in[3];
    const float* bh    = (const float*)d_in[4];
    const float* lng   = (const float*)d_in[5];
    const float* lnb   = (const float*)d_in[6];
    const float* alpha = (const float*)d_in[7];
    const float* Whead = (const float*)d_in[8];
    const float* bhead = (const float*)d_in[9];
    float* out = (float*)d_out;

    u64t* gpart = (u64t*)d_ws;            // [2][64][512] u64 = 512 KB (poison tag never matches)
    u64t* ssdp  = gpart + (size_t)2 * BB * DH;
    u64t* cosp  = ssdp + BB;

    rnn7<<<4 * BB, 512, 0, stream>>>(z, clean, Wh, Wg, bh, lng, lnb, alpha,
                                     Whead, bhead, gpart, ssdp, cosp, out);
}